// Round 1
// baseline (223.132 us; speedup 1.0000x reference)
//
#include <hip/hip_runtime.h>

// DecodeBox: B=16, A=3, ATTRS=6, D=H=W=48, stride=2 everywhere.
// in : [B, A*ATTRS, D, H, W] fp32   (channel stride = 110592 floats)
// out: [B, A*D*H*W, 6] fp32
//
// Each thread handles a PAIR of adjacent spatial sites (s, s+1) within one
// (b, a) plane:
//   reads : 6 x float2 (coalesced; plane is contiguous in s)
//   writes: 12 contiguous floats = 3 x float4 (16B aligned since 12*i and
//           663552 are both multiples of 4 floats)

#define DHW   110592   // 48*48*48
#define HW48  2304     // 48*48
#define PAIRS 55296    // DHW/2
#define NTOT  2654208  // 16*3*PAIRS

__device__ __forceinline__ float sigm(float v) {
    return 1.0f / (1.0f + __expf(-v));
}

__global__ __launch_bounds__(256) void DecodeBox_kernel(
    const float* __restrict__ in, float* __restrict__ out) {
    int t = blockIdx.x * blockDim.x + threadIdx.x;
    if (t >= NTOT) return;

    int s2 = t % PAIRS;        // pair index within (b,a) plane
    int ba = t / PAIRS;        // b*3 + a, 0..47
    int a  = ba % 3;
    int b  = ba / 3;

    int s  = 2 * s2;           // even spatial index
    int x0 = s % 48;           // even, so x0+1 never wraps the row
    int y0 = (s / 48) % 48;
    int z0 = s / HW48;

    const float anchw = (a == 0) ? 4.0f : (a == 1) ? 8.0f : 16.0f;

    // input base: channel (b*18 + a*6), spatial offset s
    const float* ip = in + (size_t)(b * 18 + a * 6) * DHW + s;
    float2 tx = *(const float2*)(ip + 0 * DHW);
    float2 ty = *(const float2*)(ip + 1 * DHW);
    float2 tz = *(const float2*)(ip + 2 * DHW);
    float2 tl = *(const float2*)(ip + 3 * DHW);
    float2 tc = *(const float2*)(ip + 4 * DHW);
    float2 tk = *(const float2*)(ip + 5 * DHW);

    // site 0
    float bx0 = (sigm(tx.x) + (float)x0) * 2.0f;
    float by0 = (sigm(ty.x) + (float)y0) * 2.0f;
    float bz0 = (sigm(tz.x) + (float)z0) * 2.0f;
    float bl0 = __expf(tl.x) * anchw;
    float cf0 = sigm(tc.x);
    float cl0 = sigm(tk.x);
    // site 1 (x0+1, same y,z)
    float bx1 = (sigm(tx.y) + (float)(x0 + 1)) * 2.0f;
    float by1 = (sigm(ty.y) + (float)y0) * 2.0f;
    float bz1 = (sigm(tz.y) + (float)z0) * 2.0f;
    float bl1 = __expf(tl.y) * anchw;
    float cf1 = sigm(tc.y);
    float cl1 = sigm(tk.y);

    // output: 12 contiguous floats at ba*663552 + 12*s2, 16B aligned
    float4* op = (float4*)(out + (size_t)ba * (DHW * 6) + (size_t)12 * s2);
    op[0] = make_float4(bx0, by0, bz0, bl0);
    op[1] = make_float4(cf0, cl0, bx1, by1);
    op[2] = make_float4(bz1, bl1, cf1, cl1);
}

extern "C" void kernel_launch(void* const* d_in, const int* in_sizes, int n_in,
                              void* d_out, int out_size, void* d_ws, size_t ws_size,
                              hipStream_t stream) {
    const float* in = (const float*)d_in[0];
    float* out = (float*)d_out;
    const int threads = 256;
    const int blocks = (NTOT + threads - 1) / threads;  // 10368
    DecodeBox_kernel<<<blocks, threads, 0, stream>>>(in, out);
}

// Round 2
// 220.261 us; speedup vs baseline: 1.0130x; 1.0130x over previous
//
#include <hip/hip_runtime.h>

// DecodeBox: B=16, A=3, ATTRS=6, D=H=W=48, stride=2 everywhere.
// in : [B, A*ATTRS, D, H, W] fp32   (channel stride = 110592 floats)
// out: [B, A*D*H*W, 6] fp32
//
// R1 structure: 256 threads/block, 4 consecutive sites per thread
// (1024 sites/block, one (b,a) plane spans 108 blocks).
//   reads : 6 x float4 per thread (dwordx4, perfectly coalesced)
//   LDS   : 24 outputs/thread staged as 6 float4s with XOR swizzle
//   writes: 6 x float4 per thread, lane-contiguous (fully coalesced) --
//           fixes the 48B-stride store segmentation of R0.

#define DHW   110592   // 48*48*48 sites per (b,a) plane
#define HW48  2304     // 48*48
#define SPB   1024     // sites per block
#define BPP   108      // blocks per plane (110592/1024)
#define F4B   1536     // float4s per block (1024*6/4)
#define F4P   165888   // float4s per plane (110592*6/4)
#define NBLK  5184     // 48 planes * 108

__device__ __forceinline__ float sigm(float v) {
    return 1.0f / (1.0f + __expf(-v));
}

// Bank swizzle in float4 units: keeps lane-linear reads conflict-free,
// spreads the writer's stride-6 pattern over all 8 4-bank groups.
__device__ __forceinline__ int swz(int i) {
    return (i & ~7) | ((i ^ (i >> 3)) & 7);
}

__global__ __launch_bounds__(256) void DecodeBox_kernel(
    const float* __restrict__ in, float* __restrict__ out) {
    __shared__ float4 lds[F4B];

    const int tid   = threadIdx.x;
    const int blk   = blockIdx.x;
    const int p     = blk / BPP;        // b*3 + a, 0..47
    const int chunk = blk - p * BPP;    // 0..107
    const int a     = p % 3;

    const int S  = chunk * SPB + tid * 4;   // first of 4 consecutive sites
    const int x0 = S % 48;                  // multiple of 4: x0..x0+3 same row
    const float yf = (float)((S / 48) % 48);
    const float zf = (float)(S / HW48);
    const float anchw = (a == 0) ? 4.0f : (a == 1) ? 8.0f : 16.0f;

    const float* ip = in + (size_t)p * (6 * DHW) + S;
    float4 tx = *(const float4*)(ip + 0 * DHW);
    float4 ty = *(const float4*)(ip + 1 * DHW);
    float4 tz = *(const float4*)(ip + 2 * DHW);
    float4 tl = *(const float4*)(ip + 3 * DHW);
    float4 tc = *(const float4*)(ip + 4 * DHW);
    float4 tk = *(const float4*)(ip + 5 * DHW);

    const float* txp = (const float*)&tx;
    const float* typ = (const float*)&ty;
    const float* tzp = (const float*)&tz;
    const float* tlp = (const float*)&tl;
    const float* tcp = (const float*)&tc;
    const float* tkp = (const float*)&tk;

    float bx[4], by[4], bz[4], bl[4], cf[4], cl[4];
#pragma unroll
    for (int q = 0; q < 4; ++q) {
        bx[q] = (sigm(txp[q]) + (float)(x0 + q)) * 2.0f;
        by[q] = (sigm(typ[q]) + yf) * 2.0f;
        bz[q] = (sigm(tzp[q]) + zf) * 2.0f;
        bl[q] = __expf(tlp[q]) * anchw;   // exp(l) * (anchor_w/stride) * stride
        cf[q] = sigm(tcp[q]);
        cl[q] = sigm(tkp[q]);
    }

    const int wb = 6 * tid;
    lds[swz(wb + 0)] = make_float4(bx[0], by[0], bz[0], bl[0]);
    lds[swz(wb + 1)] = make_float4(cf[0], cl[0], bx[1], by[1]);
    lds[swz(wb + 2)] = make_float4(bz[1], bl[1], cf[1], cl[1]);
    lds[swz(wb + 3)] = make_float4(bx[2], by[2], bz[2], bl[2]);
    lds[swz(wb + 4)] = make_float4(cf[2], cl[2], bx[3], by[3]);
    lds[swz(wb + 5)] = make_float4(bz[3], bl[3], cf[3], cl[3]);

    __syncthreads();

    float4* op = (float4*)out + (size_t)p * F4P + (size_t)chunk * F4B;
#pragma unroll
    for (int k = 0; k < 6; ++k) {
        const int i = tid + 256 * k;
        op[i] = lds[swz(i)];
    }
}

extern "C" void kernel_launch(void* const* d_in, const int* in_sizes, int n_in,
                              void* d_out, int out_size, void* d_ws, size_t ws_size,
                              hipStream_t stream) {
    const float* in = (const float*)d_in[0];
    float* out = (float*)d_out;
    DecodeBox_kernel<<<NBLK, 256, 0, stream>>>(in, out);
}

// Round 3
// 211.840 us; speedup vs baseline: 1.0533x; 1.0398x over previous
//
#include <hip/hip_runtime.h>

// DecodeBox: B=16, A=3, ATTRS=6, D=H=W=48, stride=2 everywhere.
// in : [B, A*ATTRS, D, H, W] fp32   (channel stride = 110592 floats = 432 KB)
// out: [B, A*D*H*W, 6] fp32
//
// R2 structure (pipelined streaming):
//  - 2592 blocks x 256 threads; each block processes 2 tiles of 1024 sites.
//  - Cross-tile register prefetch: tile t+1's 6 loads issue BEFORE tile t's
//    LDS transpose + stores, and the barriers are raw s_barrier with only
//    lgkmcnt(0) (LDS) waits -- the prefetched global loads are NOT drained
//    at the barrier (unlike __syncthreads' vmcnt(0) drain). Keeps the VMEM
//    queue deep -> sustained HBM streaming.
//  - Nontemporal loads/stores: pure streaming, no reuse.

typedef float vf4 __attribute__((ext_vector_type(4)));

#define DHW    110592   // sites per (b,a) plane
#define HW48   2304
#define SPB    1024     // sites per tile
#define BPP    108      // tiles per plane
#define F4B    1536     // float4s per tile (1024*6/4)
#define F4P    165888   // float4s per plane
#define CH4    27648    // channel stride in float4 units (DHW/4)
#define TPB    2        // tiles per block
#define NBLK   2592     // 5184 tiles / 2

struct Frag { vf4 x, y, z, l, c, k; };

__device__ __forceinline__ float sigm(float v) {
    return 1.0f / (1.0f + __expf(-v));
}

// float4-granular XOR swizzle: lane-linear reads conflict-free, stride-6
// writes spread over all 8 4-bank groups.
__device__ __forceinline__ int swz(int i) {
    return (i & ~7) | ((i ^ (i >> 3)) & 7);
}

// barrier that waits LDS ops only -- leaves global loads/stores in flight
__device__ __forceinline__ void lds_barrier() {
    asm volatile("s_waitcnt lgkmcnt(0)" ::: "memory");
    __builtin_amdgcn_s_barrier();
}

__device__ __forceinline__ void load_frag(const float* __restrict__ in, int T,
                                          int tid, Frag& f) {
    const int p = T / BPP;          // (b,a) plane, 0..47
    const int chunk = T - p * BPP;  // 0..107
    const vf4* ip = (const vf4*)(in + (size_t)p * (6 * DHW) + chunk * SPB) + tid;
    f.x = __builtin_nontemporal_load(ip + 0 * CH4);
    f.y = __builtin_nontemporal_load(ip + 1 * CH4);
    f.z = __builtin_nontemporal_load(ip + 2 * CH4);
    f.l = __builtin_nontemporal_load(ip + 3 * CH4);
    f.c = __builtin_nontemporal_load(ip + 4 * CH4);
    f.k = __builtin_nontemporal_load(ip + 5 * CH4);
}

__device__ __forceinline__ void process(float* __restrict__ out, int T, int tid,
                                        const Frag& f, vf4* lds) {
    const int p = T / BPP;
    const int chunk = T - p * BPP;
    const int a = p % 3;
    const float anchw = (a == 0) ? 4.0f : (a == 1) ? 8.0f : 16.0f;
    const int S = chunk * SPB + tid * 4;      // first of 4 consecutive sites
    const float xf = (float)(S % 48);         // S multiple of 4: no row wrap
    const float yf = (float)((S / 48) % 48);
    const float zf = (float)(S / HW48);

    float bx[4], by[4], bz[4], bl[4], cf[4], cl[4];
#pragma unroll
    for (int q = 0; q < 4; ++q) {
        bx[q] = (sigm(f.x[q]) + xf + (float)q) * 2.0f;
        by[q] = (sigm(f.y[q]) + yf) * 2.0f;
        bz[q] = (sigm(f.z[q]) + zf) * 2.0f;
        bl[q] = __expf(f.l[q]) * anchw;  // exp(l) * (anchor_w/stride) * stride
        cf[q] = sigm(f.c[q]);
        cl[q] = sigm(f.k[q]);
    }

    const int wb = 6 * tid;
    lds[swz(wb + 0)] = (vf4){bx[0], by[0], bz[0], bl[0]};
    lds[swz(wb + 1)] = (vf4){cf[0], cl[0], bx[1], by[1]};
    lds[swz(wb + 2)] = (vf4){bz[1], bl[1], cf[1], cl[1]};
    lds[swz(wb + 3)] = (vf4){bx[2], by[2], bz[2], bl[2]};
    lds[swz(wb + 4)] = (vf4){cf[2], cl[2], bx[3], by[3]};
    lds[swz(wb + 5)] = (vf4){bz[3], bl[3], cf[3], cl[3]};

    lds_barrier();   // LDS writes visible; prefetched global loads untouched

    vf4* op = (vf4*)out + (size_t)p * F4P + (size_t)chunk * F4B;
#pragma unroll
    for (int kk = 0; kk < 6; ++kk) {
        const int i = tid + 256 * kk;
        __builtin_nontemporal_store(lds[swz(i)], op + i);
    }

    lds_barrier();   // LDS reads done before next tile overwrites
}

__global__ __launch_bounds__(256) void DecodeBox_kernel(
    const float* __restrict__ in, float* __restrict__ out) {
    __shared__ vf4 lds[F4B];
    const int tid = threadIdx.x;
    const int T0 = blockIdx.x * TPB;

    Frag A, B;
    load_frag(in, T0, tid, A);
#pragma unroll
    for (int t = 0; t < TPB; ++t) {
        if (t + 1 < TPB) load_frag(in, T0 + t + 1, tid, B);  // prefetch
        process(out, T0 + t, tid, A, lds);
        A = B;  // renamed away by full unroll
    }
}

extern "C" void kernel_launch(void* const* d_in, const int* in_sizes, int n_in,
                              void* d_out, int out_size, void* d_ws, size_t ws_size,
                              hipStream_t stream) {
    const float* in = (const float*)d_in[0];
    float* out = (float*)d_out;
    DecodeBox_kernel<<<NBLK, 256, 0, stream>>>(in, out);
}